// Round 3
// baseline (5652.644 us; speedup 1.0000x reference)
//
#include <hip/hip_runtime.h>
#include <cmath>

#define Wd 256
#define Hd 256
#define HWd 65536
#define NTOT 4194304
#define NACC 51

#define C_COUP (2.0f / 4194304.0f)   // 2*COUPLING/N
#define C_KIN  (0.2f / 4194304.0f)   // 2*ALPHA/N
#define C_VOID 0.0098f               // 2*GAMMA^2
#define SCFP 68719476736.0           // 2^36 fixed-point scale

// block-level reduce of phi^2 sums -> one deterministic fixed-point atomic pair
__device__ __forceinline__ void block_acc(float sumx, float sumy, float* sRed,
                                          unsigned long long* accCur) {
    for (int off = 32; off > 0; off >>= 1) {
        sumx += __shfl_down(sumx, off, 64);
        sumy += __shfl_down(sumy, off, 64);
    }
    const int tid = threadIdx.x;
    const int wid = tid >> 6;
    if ((tid & 63) == 0) { sRed[wid] = sumx; sRed[4 + wid] = sumy; }
    __syncthreads();
    if (tid == 0) {
        float fx = sRed[0] + sRed[1] + sRed[2] + sRed[3];
        float fy = sRed[4] + sRed[5] + sRed[6] + sRed[7];
        atomicAdd(&accCur[0], (unsigned long long)((double)fx * SCFP + 0.5));
        atomicAdd(&accCur[1], (unsigned long long)((double)fy * SCFP + 0.5));
    }
}

// one field: f4 strip load (36 rows x 40 cols, halo 2/4) -> c-stage (Sobel corr)
// -> d-stage (second corr) producing dK[4] and center phi pv[4] per thread
__device__ __forceinline__ void field_pass(
        const float* __restrict__ phiIn, size_t base, int x0, int y0,
        int tid, int cg, int rr,
        float (*sP)[44], float (*sC1)[35], float (*sC2)[35],
        float dK[4], float pv[4])
{
    // load: 360 tasks of float4 (36 rows x 10 groups)
#pragma unroll
    for (int k = 0; k < 2; ++k) {
        int task = tid + k * 256;
        if (task < 360) {
            int u = (task * 205) >> 11;          // task/10 exact for task<360
            int v = task - 10 * u;
            int gy = y0 - 2 + u, gx = x0 - 4 + 4 * v;
            float4 val = make_float4(0.f, 0.f, 0.f, 0.f);
            if ((unsigned)gy < 256u && (unsigned)gx < 256u)
                val = *(const float4*)(phiIn + base + (size_t)gy * Wd + gx);
            *(float4*)&sP[u][4 * v] = val;
        }
    }
    __syncthreads();
    // c-stage: 34x34 region (halo 1), scalar
#pragma unroll
    for (int k = 0; k < 5; ++k) {
        int task = tid + k * 256;
        if (task < 1156) {
            int a = (task * 1929) >> 16;         // task/34 exact for task<1156
            int b = task - 34 * a;
            int gy = y0 - 1 + a, gx = x0 - 1 + b;
            float c1 = 0.f, c2 = 0.f;
            if ((unsigned)gy < 256u && (unsigned)gx < 256u) {
                float tl = sP[a][b + 2],     tc = sP[a][b + 3],      tr = sP[a][b + 4];
                float ml = sP[a + 1][b + 2],                         mr = sP[a + 1][b + 4];
                float bl = sP[a + 2][b + 2], bc_ = sP[a + 2][b + 3], br = sP[a + 2][b + 4];
                c1 = 0.125f * (tr - tl) + 0.25f * (mr - ml) + 0.125f * (br - bl);
                c2 = 0.125f * (bl - tl) + 0.25f * (bc_ - tc) + 0.125f * (br - tr);
            }
            sC1[a][b] = c1; sC2[a][b] = c2;
        }
    }
    __syncthreads();
    // d-stage: thread -> (row rr, cols 4cg..4cg+3)
    {
        float4 p4 = *(float4*)&sP[rr + 2][4 * cg + 4];
        pv[0] = p4.x; pv[1] = p4.y; pv[2] = p4.z; pv[3] = p4.w;
#pragma unroll
        for (int j = 0; j < 4; ++j) {
            int b0 = 4 * cg + j;
            dK[j] = 0.125f * (sC1[rr][b0 + 2]     - sC1[rr][b0])
                  + 0.25f  * (sC1[rr + 1][b0 + 2] - sC1[rr + 1][b0])
                  + 0.125f * (sC1[rr + 2][b0 + 2] - sC1[rr + 2][b0])
                  + 0.125f * (sC2[rr + 2][b0]     - sC2[rr][b0])
                  + 0.25f  * (sC2[rr + 2][b0 + 1] - sC2[rr][b0 + 1])
                  + 0.125f * (sC2[rr + 2][b0 + 2] - sC2[rr][b0 + 2]);
        }
    }
    __syncthreads();
}

__global__ __launch_bounds__(256)
void k_step(const float* __restrict__ S,
            const float* __restrict__ pxin, const float* __restrict__ pyin,
            float* __restrict__ pxout, float* __restrict__ pyout,
            float* __restrict__ mx, float* __restrict__ my,
            float* __restrict__ vx, float* __restrict__ vy,
            const unsigned long long* __restrict__ accPrev,
            unsigned long long* __restrict__ accCur,
            float a_step, float inv_bc2, int write_sp, float* __restrict__ sp)
{
    __shared__ __align__(16) float sP[36][44];
    __shared__ float sC1[34][35];
    __shared__ float sC2[34][35];
    __shared__ float sRed[8];

    const int tid = threadIdx.x;
    const int cg  = tid & 7;
    const int rr  = tid >> 3;
    const int x0  = blockIdx.x * 32;
    const int y0  = blockIdx.y * 32;
    const size_t base = (size_t)blockIdx.z * HWd;

    // SSB coefs from previous step's fixed-point norm sums (uniform scalar work)
    double axd = (double)accPrev[0] * (1.0 / SCFP);
    double ayd = (double)accPrev[1] * (1.0 / SCFP);
    double nxd = sqrt(axd), nyd = sqrt(ayd);
    double pnd = nxd + nyd;
    double uu = pnd * pnd - 0.01;                 // V^2
    double sg = (uu > 0.0) ? 1.0 : ((uu < 0.0) ? -1.0 : 0.0);
    const float coefx = (float)(0.2 * sg * pnd / nxd);
    const float coefy = (float)(0.2 * sg * pnd / nyd);

    float dKx[4], dKy[4], pxa[4], pya[4];
    field_pass(pxin, base, x0, y0, tid, cg, rr, sP, sC1, sC2, dKx, pxa);
    field_pass(pyin, base, x0, y0, tid, cg, rr, sP, sC1, sC2, dKy, pya);

    // ---- pointwise grad + Adam (all global traffic as float4) ----
    const int gy = y0 + rr;
    const int gxb = x0 + 4 * cg;
    const size_t idx = base + (size_t)gy * Wd + gxb;

    float4 s4 = *(const float4*)(S + idx);
    float sa[4] = {s4.x, s4.y, s4.z, s4.w};
    const bool ok_e = (gxb + 4 < Wd);
    float sE = ok_e ? S[idx + 4] : 0.f;
    const bool ok_d = (gy + 1 < Hd);
    float4 sD = ok_d ? *(const float4*)(S + idx + Wd) : make_float4(0.f, 0.f, 0.f, 0.f);
    float sdv[4] = {sD.x, sD.y, sD.z, sD.w};

    float4 m4x = *(const float4*)(mx + idx);
    float4 v4x = *(const float4*)(vx + idx);
    float4 m4y = *(const float4*)(my + idx);
    float4 v4y = *(const float4*)(vy + idx);
    float ma[4] = {m4x.x, m4x.y, m4x.z, m4x.w};
    float va[4] = {v4x.x, v4x.y, v4x.z, v4x.w};
    float mb[4] = {m4y.x, m4y.y, m4y.z, m4y.w};
    float vb[4] = {v4y.x, v4y.y, v4y.z, v4y.w};

    float nmx[4], nvx[4], npx[4], nmy[4], nvy[4], npy[4], spv[4];
    float sumx = 0.f, sumy = 0.f;
#pragma unroll
    for (int j = 0; j < 4; ++j) {
        float dx_ = (j < 3) ? (sa[j + 1] - sa[j]) : (ok_e ? (sE - sa[3]) : 0.f);
        float dy_ = ok_d ? (sdv[j] - sa[j]) : 0.f;
        float R = pxa[j] * dx_ + pya[j] * dy_;
        float vmc = (sa[j] < 0.05f) ? C_VOID : 0.f;
        float gx_ = C_COUP * R * dx_ - C_KIN * dKx[j] + (coefx + vmc) * pxa[j];
        float gy_ = C_COUP * R * dy_ - C_KIN * dKy[j] + (coefy + vmc) * pya[j];

        float m1 = 0.9f * ma[j] + 0.1f * gx_;
        float v1 = 0.999f * va[j] + 0.001f * gx_ * gx_;
        nmx[j] = m1; nvx[j] = v1;
        npx[j] = pxa[j] - a_step * m1 / (sqrtf(v1 * inv_bc2) + 1e-8f);
        sumx += npx[j] * npx[j];

        float m2 = 0.9f * mb[j] + 0.1f * gy_;
        float v2 = 0.999f * vb[j] + 0.001f * gy_ * gy_;
        nmy[j] = m2; nvy[j] = v2;
        npy[j] = pya[j] - a_step * m2 / (sqrtf(v2 * inv_bc2) + 1e-8f);
        sumy += npy[j] * npy[j];

        spv[j] = sa[j] + R;
    }
    *(float4*)(mx + idx)    = make_float4(nmx[0], nmx[1], nmx[2], nmx[3]);
    *(float4*)(vx + idx)    = make_float4(nvx[0], nvx[1], nvx[2], nvx[3]);
    *(float4*)(pxout + idx) = make_float4(npx[0], npx[1], npx[2], npx[3]);
    *(float4*)(my + idx)    = make_float4(nmy[0], nmy[1], nmy[2], nmy[3]);
    *(float4*)(vy + idx)    = make_float4(nvy[0], nvy[1], nvy[2], nvy[3]);
    *(float4*)(pyout + idx) = make_float4(npy[0], npy[1], npy[2], npy[3]);
    if (write_sp)
        *(float4*)(sp + idx) = make_float4(spv[0], spv[1], spv[2], spv[3]);

    __syncthreads();
    block_acc(sumx, sumy, sRed, accCur);
}

__global__ __launch_bounds__(256)
void k_init(const float* __restrict__ px0, const float* __restrict__ py0,
            float* __restrict__ pxA, float* __restrict__ pyA,
            float* __restrict__ mx, float* __restrict__ my,
            float* __restrict__ vx, float* __restrict__ vy,
            unsigned long long* __restrict__ acc0)
{
    __shared__ float sRed[8];
    const int tid = threadIdx.x;
    const size_t base = (size_t)blockIdx.x * 2048;
    float4 z4 = make_float4(0.f, 0.f, 0.f, 0.f);
    float sx = 0.f, sy = 0.f;
#pragma unroll
    for (int k = 0; k < 2; ++k) {
        size_t idx = base + (size_t)(k * 1024 + tid * 4);
        float4 x = *(const float4*)(px0 + idx);
        float4 y = *(const float4*)(py0 + idx);
        *(float4*)(pxA + idx) = x;  *(float4*)(pyA + idx) = y;
        *(float4*)(mx + idx) = z4;  *(float4*)(my + idx) = z4;
        *(float4*)(vx + idx) = z4;  *(float4*)(vy + idx) = z4;
        sx += x.x * x.x + x.y * x.y + x.z * x.z + x.w * x.w;
        sy += y.x * y.x + y.y * y.y + y.z * y.z + y.w * y.w;
    }
    block_acc(sx, sy, sRed, acc0);
}

extern "C" void kernel_launch(void* const* d_in, const int* in_sizes, int n_in,
                              void* d_out, int out_size, void* d_ws, size_t ws_size,
                              hipStream_t stream) {
    (void)in_sizes; (void)n_in; (void)out_size; (void)ws_size;
    const float* S   = (const float*)d_in[0];
    const float* px0 = (const float*)d_in[1];
    const float* py0 = (const float*)d_in[2];
    float* out = (float*)d_out;

    float* sp     = out;                      // slot 0: Sp
    float* outA_x = out + (size_t)NTOT;       // slot 1: phi_x post
    float* outA_y = out + 2 * (size_t)NTOT;   // slot 2: phi_y post
    float* outB_x = out + 3 * (size_t)NTOT;   // slot 3: phi_x pre
    float* outB_y = out + 4 * (size_t)NTOT;   // slot 4: phi_y pre

    float* ws = (float*)d_ws;
    float* mx = ws;
    float* my = mx + (size_t)NTOT;
    float* vx = my + (size_t)NTOT;
    float* vy = vx + (size_t)NTOT;
    unsigned long long* acc = (unsigned long long*)(vy + (size_t)NTOT);  // [NACC][2]

    hipMemsetAsync(acc, 0, NACC * 2 * sizeof(unsigned long long), stream);

    dim3 grid(8, 8, 64), blk(256, 1, 1);

    k_init<<<2048, 256, 0, stream>>>(px0, py0, outA_x, outA_y, mx, my, vx, vy, acc);

    for (int t = 1; t <= 50; ++t) {
        double bc1 = 1.0 - pow(0.9, (double)t);
        double bc2 = 1.0 - pow(0.999, (double)t);
        float a_step = (float)(0.05 / bc1);
        float inv_bc2 = (float)(1.0 / bc2);
        bool odd = (t & 1) != 0;
        const float* pix = odd ? outA_x : outB_x;
        const float* piy = odd ? outA_y : outB_y;
        float* pox = odd ? outB_x : outA_x;
        float* poy = odd ? outB_y : outA_y;
        k_step<<<grid, blk, 0, stream>>>(S, pix, piy, pox, poy,
                                         mx, my, vx, vy,
                                         acc + 2 * (t - 1), acc + 2 * t,
                                         a_step, inv_bc2, (t == 50) ? 1 : 0, sp);
    }
}

// Round 4
// 2582.314 us; speedup vs baseline: 2.1890x; 2.1890x over previous
//
#include <hip/hip_runtime.h>
#include <cmath>

#define Wd 256
#define Hd 256
#define HWd 65536
#define NTOT 4194304
#define NACC 51
#define NSLOT 64                     // atomic slots per step, one 64B line each

#define C_COUP (2.0f / 4194304.0f)   // 2*COUPLING/N
#define C_KIN  (0.2f / 4194304.0f)   // 2*ALPHA/N
#define C_VOID 0.0098f               // 2*GAMMA^2
#define SCFP 68719476736.0           // 2^36 fixed-point scale

// block-level reduce of phi^2 sums -> one deterministic fixed-point atomic pair
// into this block's z-slot (64B-padded line; 64 blocks/slot -> low contention)
__device__ __forceinline__ void block_acc(float sumx, float sumy, float* sRed,
                                          unsigned long long* slot) {
    for (int off = 32; off > 0; off >>= 1) {
        sumx += __shfl_down(sumx, off, 64);
        sumy += __shfl_down(sumy, off, 64);
    }
    const int tid = threadIdx.x;
    const int wid = tid >> 6;
    if ((tid & 63) == 0) { sRed[wid] = sumx; sRed[4 + wid] = sumy; }
    __syncthreads();
    if (tid == 0) {
        float fx = sRed[0] + sRed[1] + sRed[2] + sRed[3];
        float fy = sRed[4] + sRed[5] + sRed[6] + sRed[7];
        atomicAdd(&slot[0], (unsigned long long)((double)fx * SCFP + 0.5));
        atomicAdd(&slot[1], (unsigned long long)((double)fy * SCFP + 0.5));
    }
}

// one field: f4 strip load (36 rows x 40 cols, halo 2/4) -> c-stage (Sobel corr)
// -> d-stage (second corr) producing dK[4] and center phi pv[4] per thread
__device__ __forceinline__ void field_pass(
        const float* __restrict__ phiIn, size_t base, int x0, int y0,
        int tid, int cg, int rr,
        float (*sP)[44], float (*sC1)[35], float (*sC2)[35],
        float dK[4], float pv[4])
{
    // load: 360 tasks of float4 (36 rows x 10 groups)
#pragma unroll
    for (int k = 0; k < 2; ++k) {
        int task = tid + k * 256;
        if (task < 360) {
            int u = (task * 205) >> 11;          // task/10 exact for task<360
            int v = task - 10 * u;
            int gy = y0 - 2 + u, gx = x0 - 4 + 4 * v;
            float4 val = make_float4(0.f, 0.f, 0.f, 0.f);
            if ((unsigned)gy < 256u && (unsigned)gx < 256u)
                val = *(const float4*)(phiIn + base + (size_t)gy * Wd + gx);
            *(float4*)&sP[u][4 * v] = val;
        }
    }
    __syncthreads();
    // c-stage: 34x34 region (halo 1), scalar
#pragma unroll
    for (int k = 0; k < 5; ++k) {
        int task = tid + k * 256;
        if (task < 1156) {
            int a = (task * 1929) >> 16;         // task/34 exact for task<1156
            int b = task - 34 * a;
            int gy = y0 - 1 + a, gx = x0 - 1 + b;
            float c1 = 0.f, c2 = 0.f;
            if ((unsigned)gy < 256u && (unsigned)gx < 256u) {
                float tl = sP[a][b + 2],     tc = sP[a][b + 3],      tr = sP[a][b + 4];
                float ml = sP[a + 1][b + 2],                         mr = sP[a + 1][b + 4];
                float bl = sP[a + 2][b + 2], bc_ = sP[a + 2][b + 3], br = sP[a + 2][b + 4];
                c1 = 0.125f * (tr - tl) + 0.25f * (mr - ml) + 0.125f * (br - bl);
                c2 = 0.125f * (bl - tl) + 0.25f * (bc_ - tc) + 0.125f * (br - tr);
            }
            sC1[a][b] = c1; sC2[a][b] = c2;
        }
    }
    __syncthreads();
    // d-stage: thread -> (row rr, cols 4cg..4cg+3)
    {
        float4 p4 = *(float4*)&sP[rr + 2][4 * cg + 4];
        pv[0] = p4.x; pv[1] = p4.y; pv[2] = p4.z; pv[3] = p4.w;
#pragma unroll
        for (int j = 0; j < 4; ++j) {
            int b0 = 4 * cg + j;
            dK[j] = 0.125f * (sC1[rr][b0 + 2]     - sC1[rr][b0])
                  + 0.25f  * (sC1[rr + 1][b0 + 2] - sC1[rr + 1][b0])
                  + 0.125f * (sC1[rr + 2][b0 + 2] - sC1[rr + 2][b0])
                  + 0.125f * (sC2[rr + 2][b0]     - sC2[rr][b0])
                  + 0.25f  * (sC2[rr + 2][b0 + 1] - sC2[rr][b0 + 1])
                  + 0.125f * (sC2[rr + 2][b0 + 2] - sC2[rr][b0 + 2]);
        }
    }
    __syncthreads();
}

__global__ __launch_bounds__(256)
void k_step(const float* __restrict__ S,
            const float* __restrict__ pxin, const float* __restrict__ pyin,
            float* __restrict__ pxout, float* __restrict__ pyout,
            float* __restrict__ mx, float* __restrict__ my,
            float* __restrict__ vx, float* __restrict__ vy,
            const unsigned long long* __restrict__ accPrev,
            unsigned long long* __restrict__ accCur,
            float a_step, float inv_bc2, int write_sp, float* __restrict__ sp)
{
    __shared__ __align__(16) float sP[36][44];
    __shared__ float sC1[34][35];
    __shared__ float sC2[34][35];
    __shared__ float sRed[8];

    const int tid = threadIdx.x;
    const int cg  = tid & 7;
    const int rr  = tid >> 3;
    const int x0  = blockIdx.x * 32;
    const int y0  = blockIdx.y * 32;
    const size_t base = (size_t)blockIdx.z * HWd;

    // SSB coefs: sum the previous step's 64 fixed-point slot pairs (uniform
    // scalar loads, integer adds -> order-independent, deterministic)
    unsigned long long axu = 0ull, ayu = 0ull;
#pragma unroll 8
    for (int i = 0; i < NSLOT; ++i) {
        axu += accPrev[i * 8];
        ayu += accPrev[i * 8 + 1];
    }
    double axd = (double)axu * (1.0 / SCFP);
    double ayd = (double)ayu * (1.0 / SCFP);
    double nxd = sqrt(axd), nyd = sqrt(ayd);
    double pnd = nxd + nyd;
    double uu = pnd * pnd - 0.01;                 // V^2
    double sg = (uu > 0.0) ? 1.0 : ((uu < 0.0) ? -1.0 : 0.0);
    const float coefx = (float)(0.2 * sg * pnd / nxd);
    const float coefy = (float)(0.2 * sg * pnd / nyd);

    float dKx[4], dKy[4], pxa[4], pya[4];
    field_pass(pxin, base, x0, y0, tid, cg, rr, sP, sC1, sC2, dKx, pxa);
    field_pass(pyin, base, x0, y0, tid, cg, rr, sP, sC1, sC2, dKy, pya);

    // ---- pointwise grad + Adam (all global traffic as float4) ----
    const int gy = y0 + rr;
    const int gxb = x0 + 4 * cg;
    const size_t idx = base + (size_t)gy * Wd + gxb;

    float4 s4 = *(const float4*)(S + idx);
    float sa[4] = {s4.x, s4.y, s4.z, s4.w};
    const bool ok_e = (gxb + 4 < Wd);
    float sE = ok_e ? S[idx + 4] : 0.f;
    const bool ok_d = (gy + 1 < Hd);
    float4 sD = ok_d ? *(const float4*)(S + idx + Wd) : make_float4(0.f, 0.f, 0.f, 0.f);
    float sdv[4] = {sD.x, sD.y, sD.z, sD.w};

    float4 m4x = *(const float4*)(mx + idx);
    float4 v4x = *(const float4*)(vx + idx);
    float4 m4y = *(const float4*)(my + idx);
    float4 v4y = *(const float4*)(vy + idx);
    float ma[4] = {m4x.x, m4x.y, m4x.z, m4x.w};
    float va[4] = {v4x.x, v4x.y, v4x.z, v4x.w};
    float mb[4] = {m4y.x, m4y.y, m4y.z, m4y.w};
    float vb[4] = {v4y.x, v4y.y, v4y.z, v4y.w};

    float nmx[4], nvx[4], npx[4], nmy[4], nvy[4], npy[4], spv[4];
    float sumx = 0.f, sumy = 0.f;
#pragma unroll
    for (int j = 0; j < 4; ++j) {
        float dx_ = (j < 3) ? (sa[j + 1] - sa[j]) : (ok_e ? (sE - sa[3]) : 0.f);
        float dy_ = ok_d ? (sdv[j] - sa[j]) : 0.f;
        float R = pxa[j] * dx_ + pya[j] * dy_;
        float vmc = (sa[j] < 0.05f) ? C_VOID : 0.f;
        float gx_ = C_COUP * R * dx_ - C_KIN * dKx[j] + (coefx + vmc) * pxa[j];
        float gy_ = C_COUP * R * dy_ - C_KIN * dKy[j] + (coefy + vmc) * pya[j];

        float m1 = 0.9f * ma[j] + 0.1f * gx_;
        float v1 = 0.999f * va[j] + 0.001f * gx_ * gx_;
        nmx[j] = m1; nvx[j] = v1;
        npx[j] = pxa[j] - a_step * m1 / (sqrtf(v1 * inv_bc2) + 1e-8f);
        sumx += npx[j] * npx[j];

        float m2 = 0.9f * mb[j] + 0.1f * gy_;
        float v2 = 0.999f * vb[j] + 0.001f * gy_ * gy_;
        nmy[j] = m2; nvy[j] = v2;
        npy[j] = pya[j] - a_step * m2 / (sqrtf(v2 * inv_bc2) + 1e-8f);
        sumy += npy[j] * npy[j];

        spv[j] = sa[j] + R;
    }
    *(float4*)(mx + idx)    = make_float4(nmx[0], nmx[1], nmx[2], nmx[3]);
    *(float4*)(vx + idx)    = make_float4(nvx[0], nvx[1], nvx[2], nvx[3]);
    *(float4*)(pxout + idx) = make_float4(npx[0], npx[1], npx[2], npx[3]);
    *(float4*)(my + idx)    = make_float4(nmy[0], nmy[1], nmy[2], nmy[3]);
    *(float4*)(vy + idx)    = make_float4(nvy[0], nvy[1], nvy[2], nvy[3]);
    *(float4*)(pyout + idx) = make_float4(npy[0], npy[1], npy[2], npy[3]);
    if (write_sp)
        *(float4*)(sp + idx) = make_float4(spv[0], spv[1], spv[2], spv[3]);

    block_acc(sumx, sumy, sRed, accCur + (size_t)blockIdx.z * 8);
}

__global__ __launch_bounds__(256)
void k_init(const float* __restrict__ px0, const float* __restrict__ py0,
            float* __restrict__ pxA, float* __restrict__ pyA,
            float* __restrict__ mx, float* __restrict__ my,
            float* __restrict__ vx, float* __restrict__ vy,
            unsigned long long* __restrict__ acc0)
{
    __shared__ float sRed[8];
    const int tid = threadIdx.x;
    const size_t base = (size_t)blockIdx.x * 2048;
    float4 z4 = make_float4(0.f, 0.f, 0.f, 0.f);
    float sx = 0.f, sy = 0.f;
#pragma unroll
    for (int k = 0; k < 2; ++k) {
        size_t idx = base + (size_t)(k * 1024 + tid * 4);
        float4 x = *(const float4*)(px0 + idx);
        float4 y = *(const float4*)(py0 + idx);
        *(float4*)(pxA + idx) = x;  *(float4*)(pyA + idx) = y;
        *(float4*)(mx + idx) = z4;  *(float4*)(my + idx) = z4;
        *(float4*)(vx + idx) = z4;  *(float4*)(vy + idx) = z4;
        sx += x.x * x.x + x.y * x.y + x.z * x.z + x.w * x.w;
        sy += y.x * y.x + y.y * y.y + y.z * y.z + y.w * y.w;
    }
    block_acc(sx, sy, sRed, acc0 + (size_t)(blockIdx.x & (NSLOT - 1)) * 8);
}

extern "C" void kernel_launch(void* const* d_in, const int* in_sizes, int n_in,
                              void* d_out, int out_size, void* d_ws, size_t ws_size,
                              hipStream_t stream) {
    (void)in_sizes; (void)n_in; (void)out_size; (void)ws_size;
    const float* S   = (const float*)d_in[0];
    const float* px0 = (const float*)d_in[1];
    const float* py0 = (const float*)d_in[2];
    float* out = (float*)d_out;

    float* sp     = out;                      // slot 0: Sp
    float* outA_x = out + (size_t)NTOT;       // slot 1: phi_x post
    float* outA_y = out + 2 * (size_t)NTOT;   // slot 2: phi_y post
    float* outB_x = out + 3 * (size_t)NTOT;   // slot 3: phi_x pre
    float* outB_y = out + 4 * (size_t)NTOT;   // slot 4: phi_y pre

    float* ws = (float*)d_ws;
    float* mx = ws;
    float* my = mx + (size_t)NTOT;
    float* vx = my + (size_t)NTOT;
    float* vy = vx + (size_t)NTOT;
    // acc: [NACC][NSLOT][8] ull — each slot pair on its own 64B line
    unsigned long long* acc = (unsigned long long*)(vy + (size_t)NTOT);

    hipMemsetAsync(acc, 0, (size_t)NACC * NSLOT * 8 * sizeof(unsigned long long), stream);

    dim3 grid(8, 8, 64), blk(256, 1, 1);

    k_init<<<2048, 256, 0, stream>>>(px0, py0, outA_x, outA_y, mx, my, vx, vy, acc);

    for (int t = 1; t <= 50; ++t) {
        double bc1 = 1.0 - pow(0.9, (double)t);
        double bc2 = 1.0 - pow(0.999, (double)t);
        float a_step = (float)(0.05 / bc1);
        float inv_bc2 = (float)(1.0 / bc2);
        bool odd = (t & 1) != 0;
        const float* pix = odd ? outA_x : outB_x;
        const float* piy = odd ? outA_y : outB_y;
        float* pox = odd ? outB_x : outA_x;
        float* poy = odd ? outB_y : outA_y;
        k_step<<<grid, blk, 0, stream>>>(S, pix, piy, pox, poy,
                                         mx, my, vx, vy,
                                         acc + (size_t)(t - 1) * NSLOT * 8,
                                         acc + (size_t)t * NSLOT * 8,
                                         a_step, inv_bc2, (t == 50) ? 1 : 0, sp);
    }
}